// Round 1
// baseline (492.265 us; speedup 1.0000x reference)
//
#include <hip/hip_runtime.h>
#include <hip/hip_bf16.h>

#define BB 16
#define NN 1024
#define CC 256

typedef __attribute__((ext_vector_type(8))) short bf16x8;
typedef __attribute__((ext_vector_type(4))) float f32x4;

__device__ __forceinline__ unsigned short f2bf(float f) {
  union { float f; unsigned u; } v; v.f = f;
  unsigned r = v.u + 0x7FFFu + ((v.u >> 16) & 1u);
  return (unsigned short)(r >> 16);
}

__global__ void cast_kernel(const float* __restrict__ src,
                            unsigned short* __restrict__ dst, int n) {
  int i = blockIdx.x * blockDim.x + threadIdx.x;
  if (i < n) dst[i] = f2bf(src[i]);
}

// Amat[(h*32+w)][n] = Wp[h][n][w]   (Wp: (32, 1024, 32) f32)
__global__ __launch_bounds__(256) void wp_transpose(const float* __restrict__ Wp,
                                                    unsigned short* __restrict__ Amat) {
  __shared__ float tile[32][33];
  int h = blockIdx.y;
  int n0 = blockIdx.x * 32;
#pragma unroll
  for (int j = 0; j < 4; j++) {
    int idx = threadIdx.x + j * 256;
    int a = idx >> 5, wc = idx & 31;
    tile[a][wc] = Wp[(size_t)h * (NN * 32) + (size_t)(n0 + a) * 32 + wc];
  }
  __syncthreads();
#pragma unroll
  for (int j = 0; j < 4; j++) {
    int idx = threadIdx.x + j * 256;
    int wc = idx >> 5, a = idx & 31;
    Amat[(size_t)(h * 32 + wc) * NN + n0 + a] = f2bf(tile[a][wc]);
  }
}

// C[m][n] = sum_k A[m][k] * Bt[n][k]  (+ bias[n]); one 16x16 MFMA tile per wave.
// TRANS: store Out[col*ldo + row] instead of Out[row*ldo + col].
template <int TRANS, int F32OUT, int BIAS>
__global__ __launch_bounds__(256) void gemm_bt(
    const unsigned short* __restrict__ A, int lda, long sA,
    const unsigned short* __restrict__ Bt, int ldb, long sB,
    const float* __restrict__ bias,
    void* __restrict__ Out, int ldo, long sO, int K) {
  int b = blockIdx.z;
  int m0 = blockIdx.x * 64 + (int)(threadIdx.x >> 6) * 16;
  int n0 = blockIdx.y * 16;
  int lane = threadIdx.x & 63;
  int r = lane & 15, g = lane >> 4;
  const unsigned short* arow = A + (long)b * sA + (long)(m0 + r) * lda + g * 8;
  const unsigned short* brow = Bt + (long)b * sB + (long)(n0 + r) * ldb + g * 8;
  f32x4 acc = {0.f, 0.f, 0.f, 0.f};
  for (int k0 = 0; k0 < K; k0 += 32) {
    bf16x8 av = *(const bf16x8*)(arow + k0);
    bf16x8 bv = *(const bf16x8*)(brow + k0);
    acc = __builtin_amdgcn_mfma_f32_16x16x32_bf16(av, bv, acc, 0, 0, 0);
  }
  int col = n0 + r;
  float bias_v = BIAS ? bias[col] : 0.0f;
#pragma unroll
  for (int rr = 0; rr < 4; rr++) {
    int row = m0 + g * 4 + rr;
    float val = acc[rr] + bias_v;
    long oidx = (long)b * sO + (TRANS ? ((long)col * ldo + row) : ((long)row * ldo + col));
    if (F32OUT)
      ((float*)Out)[oidx] = val;
    else
      ((unsigned short*)Out)[oidx] = f2bf(val);
  }
}

// Fused scores + softmax: block = 16 Q-rows of one batch; wave w covers K-cols
// [256w, 256w+256). Each wave holds a 16x256 f32 score strip in registers.
__global__ __launch_bounds__(256) void attn_softmax(
    const unsigned short* __restrict__ Q,   // [B][1024][256] bf16
    const unsigned short* __restrict__ Km,  // [B][1024][256] bf16
    unsigned short* __restrict__ P) {       // [B][1024][1024] bf16
  int b = blockIdx.y;
  int n0 = blockIdx.x * 16;
  int w = threadIdx.x >> 6;
  int lane = threadIdx.x & 63;
  int r = lane & 15, g = lane >> 4;
  const unsigned short* qrow = Q + ((long)b * NN + n0 + r) * CC + g * 8;
  const unsigned short* krow = Km + ((long)b * NN + w * 256 + r) * CC + g * 8;
  f32x4 acc[16];
#pragma unroll
  for (int t = 0; t < 16; t++) acc[t] = (f32x4){0.f, 0.f, 0.f, 0.f};
  for (int k0 = 0; k0 < CC; k0 += 32) {
    bf16x8 av = *(const bf16x8*)(qrow + k0);
#pragma unroll
    for (int t = 0; t < 16; t++) {
      bf16x8 bv = *(const bf16x8*)(krow + (long)t * 16 * CC + k0);
      acc[t] = __builtin_amdgcn_mfma_f32_16x16x32_bf16(av, bv, acc[t], 0, 0, 0);
    }
  }
  __shared__ float red[4][16];
  float mrow[4];
#pragma unroll
  for (int rr = 0; rr < 4; rr++) {
    float m = acc[0][rr];
#pragma unroll
    for (int t = 1; t < 16; t++) m = fmaxf(m, acc[t][rr]);
#pragma unroll
    for (int d = 1; d < 16; d <<= 1) m = fmaxf(m, __shfl_xor(m, d, 64));
    mrow[rr] = m;
  }
  if (r == 0) {
#pragma unroll
    for (int rr = 0; rr < 4; rr++) red[w][g * 4 + rr] = mrow[rr];
  }
  __syncthreads();
#pragma unroll
  for (int rr = 0; rr < 4; rr++) {
    float m = red[0][g * 4 + rr];
#pragma unroll
    for (int w2 = 1; w2 < 4; w2++) m = fmaxf(m, red[w2][g * 4 + rr]);
    mrow[rr] = m;
  }
  __syncthreads();  // WAR: all reads of max done before sum overwrites red
  float srow[4];
#pragma unroll
  for (int rr = 0; rr < 4; rr++) {
    float s = 0.f;
#pragma unroll
    for (int t = 0; t < 16; t++) {
      float e = exp2f((acc[t][rr] - mrow[rr]) * 1.44269504088896f);
      acc[t][rr] = e;
      s += e;
    }
#pragma unroll
    for (int d = 1; d < 16; d <<= 1) s += __shfl_xor(s, d, 64);
    srow[rr] = s;
  }
  if (r == 0) {
#pragma unroll
    for (int rr = 0; rr < 4; rr++) red[w][g * 4 + rr] = srow[rr];
  }
  __syncthreads();
#pragma unroll
  for (int rr = 0; rr < 4; rr++) {
    float s = red[0][g * 4 + rr] + red[1][g * 4 + rr] + red[2][g * 4 + rr] + red[3][g * 4 + rr];
    float inv = 1.0f / s;
    int row = n0 + g * 4 + rr;
#pragma unroll
    for (int t = 0; t < 16; t++) {
      P[((long)b * NN + row) * NN + w * 256 + t * 16 + r] = f2bf(acc[t][rr] * inv);
    }
  }
}

extern "C" void kernel_launch(void* const* d_in, const int* in_sizes, int n_in,
                              void* d_out, int out_size, void* d_ws, size_t ws_size,
                              hipStream_t stream) {
  const float* x  = (const float*)d_in[0];
  const float* Wq = (const float*)d_in[1];
  const float* bq = (const float*)d_in[2];
  const float* Wk = (const float*)d_in[3];
  const float* bk = (const float*)d_in[4];
  const float* Wv = (const float*)d_in[5];
  const float* bv = (const float*)d_in[6];
  const float* Wp = (const float*)d_in[7];
  float* out = (float*)d_out;

  const long BNC = (long)BB * NN * CC;  // 4,194,304
  const long BNN = (long)BB * NN * NN;  // 16,777,216

  char* p = (char*)d_ws;
  unsigned short* xb   = (unsigned short*)p; p += BNC * 2;
  unsigned short* wqb  = (unsigned short*)p; p += CC * CC * 2;
  unsigned short* wkb  = (unsigned short*)p; p += CC * CC * 2;
  unsigned short* wvb  = (unsigned short*)p; p += CC * CC * 2;
  unsigned short* Amat = (unsigned short*)p; p += (long)NN * NN * 2;
  unsigned short* Qb   = (unsigned short*)p; p += BNC * 2;
  unsigned short* Kb   = (unsigned short*)p; p += BNC * 2;
  unsigned short* Vtb  = (unsigned short*)p; p += BNC * 2;   // [b][c][n]
  unsigned short* Pb   = (unsigned short*)p; p += BNN * 2;   // [b][n][m]
  unsigned short* QKVt = (unsigned short*)p; p += BNC * 2;   // [b][c][n]

  // Stage 0: casts + Wp transpose
  cast_kernel<<<(int)((BNC + 255) / 256), 256, 0, stream>>>(x, xb, (int)BNC);
  cast_kernel<<<(CC * CC + 255) / 256, 256, 0, stream>>>(Wq, wqb, CC * CC);
  cast_kernel<<<(CC * CC + 255) / 256, 256, 0, stream>>>(Wk, wkb, CC * CC);
  cast_kernel<<<(CC * CC + 255) / 256, 256, 0, stream>>>(Wv, wvb, CC * CC);
  wp_transpose<<<dim3(NN / 32, 32), 256, 0, stream>>>(Wp, Amat);

  dim3 gproj(NN / 64, CC / 16, BB);  // M=1024, N=256 per batch
  // Q = x @ Wq^T + bq  (row-major bf16)
  gemm_bt<0, 0, 1><<<gproj, 256, 0, stream>>>(xb, CC, (long)NN * CC, wqb, CC, 0L, bq,
                                              Qb, CC, (long)NN * CC, CC);
  // K = x @ Wk^T + bk
  gemm_bt<0, 0, 1><<<gproj, 256, 0, stream>>>(xb, CC, (long)NN * CC, wkb, CC, 0L, bk,
                                              Kb, CC, (long)NN * CC, CC);
  // Vt = (x @ Wv^T + bv)^T  -> [c][n]
  gemm_bt<1, 0, 1><<<gproj, 256, 0, stream>>>(xb, CC, (long)NN * CC, wvb, CC, 0L, bv,
                                              Vtb, NN, (long)NN * CC, CC);

  // P = softmax(Q K^T) per batch, fused (scores never leave registers)
  attn_softmax<<<dim3(NN / 16, BB), 256, 0, stream>>>(Qb, Kb, Pb);

  // QKVt = (P @ V)^T -> [c][n];  A=P (n x m), Bt=Vt (c x m)
  gemm_bt<1, 0, 0><<<gproj, 256, 0, stream>>>(Pb, NN, (long)NN * NN, Vtb, NN, (long)NN * CC,
                                              nullptr, QKVt, NN, (long)NN * CC, NN);
  // Z = Amat @ QKV -> f32 out;  A=Amat (hw x n, batch-shared), Bt=QKVt (c x n)
  gemm_bt<0, 1, 0><<<gproj, 256, 0, stream>>>(Amat, NN, 0L, QKVt, NN, (long)NN * CC,
                                              nullptr, out, CC, (long)NN * CC, NN);
}

// Round 2
// 230.581 us; speedup vs baseline: 2.1349x; 2.1349x over previous
//
#include <hip/hip_runtime.h>
#include <hip/hip_bf16.h>

#define BB 16
#define NN 1024
#define CC 256

typedef __attribute__((ext_vector_type(8))) short bf16x8;
typedef __attribute__((ext_vector_type(4))) float f32x4;

#define GPTR(p) ((const __attribute__((address_space(1))) void*)(p))
#define LPTR(p) ((__attribute__((address_space(3))) void*)(p))

__device__ __forceinline__ unsigned short f2bf(float f) {
  union { float f; unsigned u; } v; v.f = f;
  unsigned r = v.u + 0x7FFFu + ((v.u >> 16) & 1u);
  return (unsigned short)(r >> 16);
}

__global__ void cast_kernel(const float* __restrict__ src,
                            unsigned short* __restrict__ dst, int n) {
  int i = blockIdx.x * blockDim.x + threadIdx.x;
  if (i < n) dst[i] = f2bf(src[i]);
}

// Amat[(h*32+w)][n] = Wp[h][n][w]   (Wp: (32, 1024, 32) f32)
__global__ __launch_bounds__(256) void wp_transpose(const float* __restrict__ Wp,
                                                    unsigned short* __restrict__ Amat) {
  __shared__ float tile[32][33];
  int h = blockIdx.y;
  int n0 = blockIdx.x * 32;
#pragma unroll
  for (int j = 0; j < 4; j++) {
    int idx = threadIdx.x + j * 256;
    int a = idx >> 5, wc = idx & 31;
    tile[a][wc] = Wp[(size_t)h * (NN * 32) + (size_t)(n0 + a) * 32 + wc];
  }
  __syncthreads();
#pragma unroll
  for (int j = 0; j < 4; j++) {
    int idx = threadIdx.x + j * 256;
    int wc = idx >> 5, a = idx & 31;
    Amat[(size_t)(h * 32 + wc) * NN + n0 + a] = f2bf(tile[a][wc]);
  }
}

// Tiled GEMM: C[m][n] = sum_k A[m][k] * Bt[n][k] (+bias). BM=128 BN=64 BK=32.
// 256 threads = 2x2 waves, 64x32 per wave, 4x2 MFMA tiles of 16x16x32.
// BIAS_MODE: 0 none, 1 bias[col], 2 bias[row]. F32OUT: out dtype.
template <int BIAS_MODE, int F32OUT>
__global__ __launch_bounds__(256) void gemm_tile(
    const unsigned short* __restrict__ A, int lda, long sA,
    const unsigned short* __restrict__ Bt, int ldb, long sB,
    const float* __restrict__ bias,
    void* __restrict__ Out, int ldo, long sO, int K) {
  __shared__ unsigned short As[128 * 32];
  __shared__ unsigned short Bs[64 * 32];
  int b = blockIdx.z;
  int m0 = blockIdx.x * 128;
  int n0 = blockIdx.y * 64;
  int t = threadIdx.x;
  int w = t >> 6, lane = t & 63;
  int wm = (w >> 1) * 64, wn = (w & 1) * 32;
  int r = lane & 15, g = lane >> 4;

  const unsigned short* Ab = A + (long)b * sA;
  const unsigned short* Bb = Bt + (long)b * sB;

  // staging coords: thread t stages 8 elems (16B) at flat offset t*8
  int srow = t >> 2;            // (t*8)/32
  int scol = (t & 3) * 8;       // (t*8)%32
  const unsigned short* agp0 = Ab + (long)(m0 + srow) * lda + scol;
  const unsigned short* agp1 = Ab + (long)(m0 + srow + 64) * lda + scol;
  const unsigned short* bgp  = Bb + (long)(n0 + srow) * ldb + scol;

  f32x4 acc[4][2];
#pragma unroll
  for (int i = 0; i < 4; i++)
#pragma unroll
    for (int j = 0; j < 2; j++) acc[i][j] = (f32x4){0.f, 0.f, 0.f, 0.f};

  for (int k0 = 0; k0 < K; k0 += 32) {
    __syncthreads();
    __builtin_amdgcn_global_load_lds(GPTR(agp0 + k0), LPTR(&As[t * 8]), 16, 0, 0);
    __builtin_amdgcn_global_load_lds(GPTR(agp1 + k0), LPTR(&As[2048 + t * 8]), 16, 0, 0);
    __builtin_amdgcn_global_load_lds(GPTR(bgp + k0),  LPTR(&Bs[t * 8]), 16, 0, 0);
    __syncthreads();
    bf16x8 af[4], bfr[2];
#pragma unroll
    for (int ti = 0; ti < 4; ti++)
      af[ti] = *(const bf16x8*)&As[(wm + ti * 16 + r) * 32 + g * 8];
#pragma unroll
    for (int tj = 0; tj < 2; tj++)
      bfr[tj] = *(const bf16x8*)&Bs[(wn + tj * 16 + r) * 32 + g * 8];
#pragma unroll
    for (int ti = 0; ti < 4; ti++)
#pragma unroll
      for (int tj = 0; tj < 2; tj++)
        acc[ti][tj] = __builtin_amdgcn_mfma_f32_16x16x32_bf16(af[ti], bfr[tj], acc[ti][tj], 0, 0, 0);
  }

#pragma unroll
  for (int ti = 0; ti < 4; ti++) {
#pragma unroll
    for (int tj = 0; tj < 2; tj++) {
      int col = n0 + wn + tj * 16 + r;
      float bc = (BIAS_MODE == 1) ? bias[col] : 0.0f;
#pragma unroll
      for (int rr = 0; rr < 4; rr++) {
        int row = m0 + wm + ti * 16 + g * 4 + rr;
        float val = acc[ti][tj][rr] + bc;
        if (BIAS_MODE == 2) val += bias[row];
        long oidx = (long)b * sO + (long)row * ldo + col;
        if (F32OUT)
          ((float*)Out)[oidx] = val;
        else
          ((unsigned short*)Out)[oidx] = f2bf(val);
      }
    }
  }
}

// Fused scores + softmax: block = 16 Q-rows of one batch; wave w covers K-cols
// [256w, 256w+256). Each wave holds a 16x256 f32 score strip in registers.
__global__ __launch_bounds__(256) void attn_softmax(
    const unsigned short* __restrict__ Q,   // [B][1024][256] bf16
    const unsigned short* __restrict__ Km,  // [B][1024][256] bf16
    unsigned short* __restrict__ P) {       // [B][1024][1024] bf16
  int b = blockIdx.y;
  int n0 = blockIdx.x * 16;
  int w = threadIdx.x >> 6;
  int lane = threadIdx.x & 63;
  int r = lane & 15, g = lane >> 4;
  const unsigned short* qrow = Q + ((long)b * NN + n0 + r) * CC + g * 8;
  const unsigned short* krow = Km + ((long)b * NN + w * 256 + r) * CC + g * 8;
  f32x4 acc[16];
#pragma unroll
  for (int t = 0; t < 16; t++) acc[t] = (f32x4){0.f, 0.f, 0.f, 0.f};
  for (int k0 = 0; k0 < CC; k0 += 32) {
    bf16x8 av = *(const bf16x8*)(qrow + k0);
#pragma unroll
    for (int t = 0; t < 16; t++) {
      bf16x8 bv = *(const bf16x8*)(krow + (long)t * 16 * CC + k0);
      acc[t] = __builtin_amdgcn_mfma_f32_16x16x32_bf16(av, bv, acc[t], 0, 0, 0);
    }
  }
  __shared__ float red[4][16];
  float mrow[4];
#pragma unroll
  for (int rr = 0; rr < 4; rr++) {
    float m = acc[0][rr];
#pragma unroll
    for (int t = 1; t < 16; t++) m = fmaxf(m, acc[t][rr]);
#pragma unroll
    for (int d = 1; d < 16; d <<= 1) m = fmaxf(m, __shfl_xor(m, d, 64));
    mrow[rr] = m;
  }
  if (r == 0) {
#pragma unroll
    for (int rr = 0; rr < 4; rr++) red[w][g * 4 + rr] = mrow[rr];
  }
  __syncthreads();
#pragma unroll
  for (int rr = 0; rr < 4; rr++) {
    float m = red[0][g * 4 + rr];
#pragma unroll
    for (int w2 = 1; w2 < 4; w2++) m = fmaxf(m, red[w2][g * 4 + rr]);
    mrow[rr] = m;
  }
  __syncthreads();  // WAR: all reads of max done before sum overwrites red
  float srow[4];
#pragma unroll
  for (int rr = 0; rr < 4; rr++) {
    float s = 0.f;
#pragma unroll
    for (int t = 0; t < 16; t++) {
      float e = exp2f((acc[t][rr] - mrow[rr]) * 1.44269504088896f);
      acc[t][rr] = e;
      s += e;
    }
#pragma unroll
    for (int d = 1; d < 16; d <<= 1) s += __shfl_xor(s, d, 64);
    srow[rr] = s;
  }
  if (r == 0) {
#pragma unroll
    for (int rr = 0; rr < 4; rr++) red[w][g * 4 + rr] = srow[rr];
  }
  __syncthreads();
#pragma unroll
  for (int rr = 0; rr < 4; rr++) {
    float s = red[0][g * 4 + rr] + red[1][g * 4 + rr] + red[2][g * 4 + rr] + red[3][g * 4 + rr];
    float inv = 1.0f / s;
    int row = n0 + g * 4 + rr;
#pragma unroll
    for (int t = 0; t < 16; t++) {
      P[((long)b * NN + row) * NN + w * 256 + t * 16 + r] = f2bf(acc[t][rr] * inv);
    }
  }
}

extern "C" void kernel_launch(void* const* d_in, const int* in_sizes, int n_in,
                              void* d_out, int out_size, void* d_ws, size_t ws_size,
                              hipStream_t stream) {
  const float* x  = (const float*)d_in[0];
  const float* Wq = (const float*)d_in[1];
  const float* bq = (const float*)d_in[2];
  const float* Wk = (const float*)d_in[3];
  const float* bk = (const float*)d_in[4];
  const float* Wv = (const float*)d_in[5];
  const float* bv = (const float*)d_in[6];
  const float* Wp = (const float*)d_in[7];
  float* out = (float*)d_out;

  const long BNC = (long)BB * NN * CC;  // 4,194,304
  const long BNN = (long)BB * NN * NN;  // 16,777,216

  char* p = (char*)d_ws;
  unsigned short* xb   = (unsigned short*)p; p += BNC * 2;
  unsigned short* wqb  = (unsigned short*)p; p += CC * CC * 2;
  unsigned short* wkb  = (unsigned short*)p; p += CC * CC * 2;
  unsigned short* wvb  = (unsigned short*)p; p += CC * CC * 2;
  unsigned short* Amat = (unsigned short*)p; p += (long)NN * NN * 2;
  unsigned short* Qb   = (unsigned short*)p; p += BNC * 2;
  unsigned short* Kb   = (unsigned short*)p; p += BNC * 2;
  unsigned short* Vtb  = (unsigned short*)p; p += BNC * 2;   // [b][c][n]
  unsigned short* Pb   = (unsigned short*)p; p += BNN * 2;   // [b][n][m]
  unsigned short* QKVt = (unsigned short*)p; p += BNC * 2;   // [b][c][n]

  // Stage 0: casts + Wp transpose
  cast_kernel<<<(int)((BNC + 255) / 256), 256, 0, stream>>>(x, xb, (int)BNC);
  cast_kernel<<<(CC * CC + 255) / 256, 256, 0, stream>>>(Wq, wqb, CC * CC);
  cast_kernel<<<(CC * CC + 255) / 256, 256, 0, stream>>>(Wk, wkb, CC * CC);
  cast_kernel<<<(CC * CC + 255) / 256, 256, 0, stream>>>(Wv, wvb, CC * CC);
  wp_transpose<<<dim3(NN / 32, 32), 256, 0, stream>>>(Wp, Amat);

  // Q = x @ Wq^T + bq : M=1024 (tokens), N=256 (c), K=256 -> [b][n][c]
  gemm_tile<1, 0><<<dim3(8, 4, BB), 256, 0, stream>>>(
      xb, CC, (long)NN * CC, wqb, CC, 0L, bq, Qb, CC, (long)NN * CC, CC);
  // K = x @ Wk^T + bk
  gemm_tile<1, 0><<<dim3(8, 4, BB), 256, 0, stream>>>(
      xb, CC, (long)NN * CC, wkb, CC, 0L, bk, Kb, CC, (long)NN * CC, CC);
  // Vt[c][n] = Wv[c].x[n] + bv[c] : M=256 (c), N=1024 (tokens), row bias
  gemm_tile<2, 0><<<dim3(2, 16, BB), 256, 0, stream>>>(
      wvb, CC, 0L, xb, CC, (long)NN * CC, bv, Vtb, NN, (long)NN * CC, CC);

  // P = softmax(Q K^T) per batch, fused (scores never leave registers)
  attn_softmax<<<dim3(NN / 16, BB), 256, 0, stream>>>(Qb, Kb, Pb);

  // QKVt[c][n] = sum_m Vt[c][m] * P[n][m] : M=256, N=1024, K=1024
  gemm_tile<0, 0><<<dim3(2, 16, BB), 256, 0, stream>>>(
      Vtb, NN, (long)NN * CC, Pb, NN, (long)NN * NN, nullptr,
      QKVt, NN, (long)NN * CC, NN);
  // Z[hw][c] = sum_n Amat[hw][n] * QKVt[c][n] : M=1024, N=256, K=1024, f32 out
  gemm_tile<0, 1><<<dim3(8, 4, BB), 256, 0, stream>>>(
      Amat, NN, 0L, QKVt, NN, (long)NN * CC, nullptr,
      out, CC, (long)NN * CC, NN);
}

// Round 4
// 193.764 us; speedup vs baseline: 2.5405x; 1.1900x over previous
//
#include <hip/hip_runtime.h>
#include <hip/hip_bf16.h>

#define BB 16
#define NN 1024
#define CC 256

typedef __attribute__((ext_vector_type(8))) short bf16x8;
typedef __attribute__((ext_vector_type(4))) float f32x4;

#define GPTR(p) ((const __attribute__((address_space(1))) void*)(p))
#define LPTR(p) ((__attribute__((address_space(3))) void*)(p))

__device__ __forceinline__ unsigned short f2bf(float f) {
  union { float f; unsigned u; } v; v.f = f;
  unsigned r = v.u + 0x7FFFu + ((v.u >> 16) & 1u);
  return (unsigned short)(r >> 16);
}

__global__ void cast_kernel(const float* __restrict__ src,
                            unsigned short* __restrict__ dst, int n) {
  int i = blockIdx.x * blockDim.x + threadIdx.x;
  if (i < n) dst[i] = f2bf(src[i]);
}

// Amat[(h*32+w)][n] = Wp[h][n][w]   (Wp: (32, 1024, 32) f32)
__global__ __launch_bounds__(256) void wp_transpose(const float* __restrict__ Wp,
                                                    unsigned short* __restrict__ Amat) {
  __shared__ float tile[32][33];
  int h = blockIdx.y;
  int n0 = blockIdx.x * 32;
#pragma unroll
  for (int j = 0; j < 4; j++) {
    int idx = threadIdx.x + j * 256;
    int a = idx >> 5, wc = idx & 31;
    tile[a][wc] = Wp[(size_t)h * (NN * 32) + (size_t)(n0 + a) * 32 + wc];
  }
  __syncthreads();
#pragma unroll
  for (int j = 0; j < 4; j++) {
    int idx = threadIdx.x + j * 256;
    int wc = idx >> 5, a = idx & 31;
    Amat[(size_t)(h * 32 + wc) * NN + n0 + a] = f2bf(tile[a][wc]);
  }
}

// Tiled GEMM: C[m][n] = sum_k A[m][k] * Bt[n][k] (+bias). BM=128 BN=64 BK=32.
template <int BIAS_MODE, int F32OUT>
__global__ __launch_bounds__(256) void gemm_tile(
    const unsigned short* __restrict__ A, int lda, long sA,
    const unsigned short* __restrict__ Bt, int ldb, long sB,
    const float* __restrict__ bias,
    void* __restrict__ Out, int ldo, long sO, int K) {
  __shared__ unsigned short As[128 * 32];
  __shared__ unsigned short Bs[64 * 32];
  int b = blockIdx.z;
  int m0 = blockIdx.x * 128;
  int n0 = blockIdx.y * 64;
  int t = threadIdx.x;
  int w = t >> 6, lane = t & 63;
  int wm = (w >> 1) * 64, wn = (w & 1) * 32;
  int r = lane & 15, g = lane >> 4;

  const unsigned short* Ab = A + (long)b * sA;
  const unsigned short* Bb = Bt + (long)b * sB;

  int srow = t >> 2;
  int scol = (t & 3) * 8;
  const unsigned short* agp0 = Ab + (long)(m0 + srow) * lda + scol;
  const unsigned short* agp1 = Ab + (long)(m0 + srow + 64) * lda + scol;
  const unsigned short* bgp  = Bb + (long)(n0 + srow) * ldb + scol;

  f32x4 acc[4][2];
#pragma unroll
  for (int i = 0; i < 4; i++)
#pragma unroll
    for (int j = 0; j < 2; j++) acc[i][j] = (f32x4){0.f, 0.f, 0.f, 0.f};

  for (int k0 = 0; k0 < K; k0 += 32) {
    __syncthreads();
    __builtin_amdgcn_global_load_lds(GPTR(agp0 + k0), LPTR(&As[t * 8]), 16, 0, 0);
    __builtin_amdgcn_global_load_lds(GPTR(agp1 + k0), LPTR(&As[2048 + t * 8]), 16, 0, 0);
    __builtin_amdgcn_global_load_lds(GPTR(bgp + k0),  LPTR(&Bs[t * 8]), 16, 0, 0);
    __syncthreads();
    bf16x8 af[4], bfr[2];
#pragma unroll
    for (int ti = 0; ti < 4; ti++)
      af[ti] = *(const bf16x8*)&As[(wm + ti * 16 + r) * 32 + g * 8];
#pragma unroll
    for (int tj = 0; tj < 2; tj++)
      bfr[tj] = *(const bf16x8*)&Bs[(wn + tj * 16 + r) * 32 + g * 8];
#pragma unroll
    for (int ti = 0; ti < 4; ti++)
#pragma unroll
      for (int tj = 0; tj < 2; tj++)
        acc[ti][tj] = __builtin_amdgcn_mfma_f32_16x16x32_bf16(af[ti], bfr[tj], acc[ti][tj], 0, 0, 0);
  }

#pragma unroll
  for (int ti = 0; ti < 4; ti++) {
#pragma unroll
    for (int tj = 0; tj < 2; tj++) {
      int col = n0 + wn + tj * 16 + r;
      float bc = (BIAS_MODE == 1) ? bias[col] : 0.0f;
#pragma unroll
      for (int rr = 0; rr < 4; rr++) {
        int row = m0 + wm + ti * 16 + g * 4 + rr;
        float val = acc[ti][tj][rr] + bc;
        if (BIAS_MODE == 2) val += bias[row];
        long oidx = (long)b * sO + (long)row * ldo + col;
        if (F32OUT)
          ((float*)Out)[oidx] = val;
        else
          ((unsigned short*)Out)[oidx] = f2bf(val);
      }
    }
  }
}

// Fused scores+softmax v2: block = 32 Q-rows x 1024 K-cols, 512 threads.
// 8 waves = 2 row-groups x 4 col-sections of 256. K slab (1024x32, 64 KB)
// staged in LDS per k-step via global_load_lds; Q preloaded to registers.
__global__ __launch_bounds__(512, 4) void attn_softmax_v2(
    const unsigned short* __restrict__ Q,   // [B][1024][256] bf16
    const unsigned short* __restrict__ Km,  // [B][1024][256] bf16
    unsigned short* __restrict__ P) {       // [B][1024][1024] bf16
  __shared__ unsigned short Ks[1024 * 32];  // 64 KB
  __shared__ float red[4][2][16];           // [col-section][row-group][row]
  int b = blockIdx.y;
  int n0 = blockIdx.x * 32;
  int t = threadIdx.x;
  int w = t >> 6, lane = t & 63;
  int rg = w >> 2, ch = w & 3;
  int r = lane & 15, g = lane >> 4;

  // Preload this wave's Q strip (16 rows x 256 k) as 8 A-fragments.
  const unsigned short* qbase = Q + ((long)b * NN + n0 + rg * 16 + r) * CC + g * 8;
  bf16x8 qf[8];
#pragma unroll
  for (int kk = 0; kk < 8; kk++) qf[kk] = *(const bf16x8*)(qbase + kk * 32);

  const unsigned short* kbase = Km + (long)b * NN * CC;
  int strow = t >> 2;           // 0..127
  int stcol = (t & 3) * 8;

  f32x4 acc[16];
#pragma unroll
  for (int tt = 0; tt < 16; tt++) acc[tt] = (f32x4){0.f, 0.f, 0.f, 0.f};

  for (int kk = 0; kk < 8; kk++) {
    __syncthreads();
#pragma unroll
    for (int jj = 0; jj < 8; jj++) {
      __builtin_amdgcn_global_load_lds(
          GPTR(kbase + (long)(strow + jj * 128) * CC + kk * 32 + stcol),
          LPTR(&Ks[(strow + jj * 128) * 32 + stcol]), 16, 0, 0);
    }
    __syncthreads();
#pragma unroll
    for (int tt = 0; tt < 16; tt++) {
      bf16x8 bv = *(const bf16x8*)&Ks[(ch * 256 + tt * 16 + r) * 32 + g * 8];
      acc[tt] = __builtin_amdgcn_mfma_f32_16x16x32_bf16(qf[kk], bv, acc[tt], 0, 0, 0);
    }
  }

  // ---- softmax over each full row (reduce within wave, then across ch) ----
  float mrow[4];
#pragma unroll
  for (int rr = 0; rr < 4; rr++) {
    float m = acc[0][rr];
#pragma unroll
    for (int tt = 1; tt < 16; tt++) m = fmaxf(m, acc[tt][rr]);
#pragma unroll
    for (int d = 1; d < 16; d <<= 1) m = fmaxf(m, __shfl_xor(m, d, 64));
    mrow[rr] = m;
  }
  if (r == 0) {
#pragma unroll
    for (int rr = 0; rr < 4; rr++) red[ch][rg][g * 4 + rr] = mrow[rr];
  }
  __syncthreads();
#pragma unroll
  for (int rr = 0; rr < 4; rr++) {
    float m = red[0][rg][g * 4 + rr];
#pragma unroll
    for (int c2 = 1; c2 < 4; c2++) m = fmaxf(m, red[c2][rg][g * 4 + rr]);
    mrow[rr] = m;
  }
  __syncthreads();  // WAR: all max reads done before sum overwrites red
  float ssum[4];
#pragma unroll
  for (int rr = 0; rr < 4; rr++) {
    float s = 0.f;
#pragma unroll
    for (int tt = 0; tt < 16; tt++) {
      float e = exp2f((acc[tt][rr] - mrow[rr]) * 1.44269504088896f);
      acc[tt][rr] = e;
      s += e;
    }
#pragma unroll
    for (int d = 1; d < 16; d <<= 1) s += __shfl_xor(s, d, 64);
    ssum[rr] = s;
  }
  if (r == 0) {
#pragma unroll
    for (int rr = 0; rr < 4; rr++) red[ch][rg][g * 4 + rr] = ssum[rr];
  }
  __syncthreads();
#pragma unroll
  for (int rr = 0; rr < 4; rr++) {
    float s = red[0][rg][g * 4 + rr] + red[1][rg][g * 4 + rr] +
              red[2][rg][g * 4 + rr] + red[3][rg][g * 4 + rr];
    float inv = 1.0f / s;
    int row = n0 + rg * 16 + g * 4 + rr;
#pragma unroll
    for (int tt = 0; tt < 16; tt++) {
      P[((long)b * NN + row) * NN + ch * 256 + tt * 16 + r] = f2bf(acc[tt][rr] * inv);
    }
  }
}

extern "C" void kernel_launch(void* const* d_in, const int* in_sizes, int n_in,
                              void* d_out, int out_size, void* d_ws, size_t ws_size,
                              hipStream_t stream) {
  const float* x  = (const float*)d_in[0];
  const float* Wq = (const float*)d_in[1];
  const float* bq = (const float*)d_in[2];
  const float* Wk = (const float*)d_in[3];
  const float* bk = (const float*)d_in[4];
  const float* Wv = (const float*)d_in[5];
  const float* bv = (const float*)d_in[6];
  const float* Wp = (const float*)d_in[7];
  float* out = (float*)d_out;

  const long BNC = (long)BB * NN * CC;  // 4,194,304
  const long BNN = (long)BB * NN * NN;  // 16,777,216

  char* p = (char*)d_ws;
  unsigned short* xb   = (unsigned short*)p; p += BNC * 2;
  unsigned short* wqb  = (unsigned short*)p; p += CC * CC * 2;
  unsigned short* wkb  = (unsigned short*)p; p += CC * CC * 2;
  unsigned short* wvb  = (unsigned short*)p; p += CC * CC * 2;
  unsigned short* Amat = (unsigned short*)p; p += (long)NN * NN * 2;
  unsigned short* Qb   = (unsigned short*)p; p += BNC * 2;
  unsigned short* Kb   = (unsigned short*)p; p += BNC * 2;
  unsigned short* Vtb  = (unsigned short*)p; p += BNC * 2;   // [b][c][n]
  unsigned short* Pb   = (unsigned short*)p; p += BNN * 2;   // [b][n][m]
  unsigned short* QKVt = (unsigned short*)p; p += BNC * 2;   // [b][c][n]

  // Stage 0: casts + Wp transpose
  cast_kernel<<<(int)((BNC + 255) / 256), 256, 0, stream>>>(x, xb, (int)BNC);
  cast_kernel<<<(CC * CC + 255) / 256, 256, 0, stream>>>(Wq, wqb, CC * CC);
  cast_kernel<<<(CC * CC + 255) / 256, 256, 0, stream>>>(Wk, wkb, CC * CC);
  cast_kernel<<<(CC * CC + 255) / 256, 256, 0, stream>>>(Wv, wvb, CC * CC);
  wp_transpose<<<dim3(NN / 32, 32), 256, 0, stream>>>(Wp, Amat);

  // Q = x @ Wq^T + bq : M=1024 (tokens), N=256 (c), K=256 -> [b][n][c]
  gemm_tile<1, 0><<<dim3(8, 4, BB), 256, 0, stream>>>(
      xb, CC, (long)NN * CC, wqb, CC, 0L, bq, Qb, CC, (long)NN * CC, CC);
  // K = x @ Wk^T + bk
  gemm_tile<1, 0><<<dim3(8, 4, BB), 256, 0, stream>>>(
      xb, CC, (long)NN * CC, wkb, CC, 0L, bk, Kb, CC, (long)NN * CC, CC);
  // Vt[c][n] = Wv[c].x[n] + bv[c] : M=256 (c), N=1024 (tokens), row bias
  gemm_tile<2, 0><<<dim3(2, 16, BB), 256, 0, stream>>>(
      wvb, CC, 0L, xb, CC, (long)NN * CC, bv, Vtb, NN, (long)NN * CC, CC);

  // P = softmax(Q K^T) per batch, fused (scores never leave registers)
  attn_softmax_v2<<<dim3(NN / 32, BB), 512, 0, stream>>>(Qb, Kb, Pb);

  // QKVt[c][n] = sum_m Vt[c][m] * P[n][m] : M=256, N=1024, K=1024
  gemm_tile<0, 0><<<dim3(2, 16, BB), 256, 0, stream>>>(
      Vtb, NN, (long)NN * CC, Pb, NN, (long)NN * NN, nullptr,
      QKVt, NN, (long)NN * CC, NN);
  // Z[hw][c] = sum_n Amat[hw][n] * QKVt[c][n] : M=1024, N=256, K=1024, f32 out
  gemm_tile<0, 1><<<dim3(8, 4, BB), 256, 0, stream>>>(
      Amat, NN, 0L, QKVt, NN, (long)NN * CC, nullptr,
      out, CC, (long)NN * CC, NN);
}

// Round 5
// 186.695 us; speedup vs baseline: 2.6367x; 1.0379x over previous
//
#include <hip/hip_runtime.h>
#include <hip/hip_bf16.h>

#define BB 16
#define NN 1024
#define CC 256

typedef __attribute__((ext_vector_type(8))) short bf16x8;
typedef __attribute__((ext_vector_type(4))) float f32x4;

#define GPTR(p) ((const __attribute__((address_space(1))) void*)(p))
#define LPTR(p) ((__attribute__((address_space(3))) void*)(p))

__device__ __forceinline__ unsigned short f2bf(float f) {
  union { float f; unsigned u; } v; v.f = f;
  unsigned r = v.u + 0x7FFFu + ((v.u >> 16) & 1u);
  return (unsigned short)(r >> 16);
}

__global__ void cast_kernel(const float* __restrict__ src,
                            unsigned short* __restrict__ dst, int n) {
  int i = blockIdx.x * blockDim.x + threadIdx.x;
  if (i < n) dst[i] = f2bf(src[i]);
}

// Amat[(h*32+w)][n] = Wp[h][n][w]   (Wp: (32, 1024, 32) f32)
__global__ __launch_bounds__(256) void wp_transpose(const float* __restrict__ Wp,
                                                    unsigned short* __restrict__ Amat) {
  __shared__ float tile[32][33];
  int h = blockIdx.y;
  int n0 = blockIdx.x * 32;
#pragma unroll
  for (int j = 0; j < 4; j++) {
    int idx = threadIdx.x + j * 256;
    int a = idx >> 5, wc = idx & 31;
    tile[a][wc] = Wp[(size_t)h * (NN * 32) + (size_t)(n0 + a) * 32 + wc];
  }
  __syncthreads();
#pragma unroll
  for (int j = 0; j < 4; j++) {
    int idx = threadIdx.x + j * 256;
    int wc = idx >> 5, a = idx & 31;
    Amat[(size_t)(h * 32 + wc) * NN + n0 + a] = f2bf(tile[a][wc]);
  }
}

// Tiled GEMM: C[m][n] = sum_k A[m][k] * Bt[n][k] (+bias). BM=128 BN=64 BK=64.
// LDS as two k-panels of [rows][32] so global_load_lds stays lane-linear and
// ds_read_b128 stays conflict-free. 256 thr = 2x2 waves, 64x32 per wave.
template <int BIAS_MODE, int F32OUT>
__global__ __launch_bounds__(256) void gemm_tile(
    const unsigned short* __restrict__ A, int lda, long sA,
    const unsigned short* __restrict__ Bt, int ldb, long sB,
    const float* __restrict__ bias,
    void* __restrict__ Out, int ldo, long sO, int K) {
  __shared__ unsigned short As[2 * 128 * 32];  // [kh][row][32] 16 KB
  __shared__ unsigned short Bs[2 * 64 * 32];   // [kh][row][32]  8 KB
  int b = blockIdx.z;
  int m0 = blockIdx.x * 128;
  int n0 = blockIdx.y * 64;
  int t = threadIdx.x;
  int w = t >> 6, lane = t & 63;
  int wm = (w >> 1) * 64, wn = (w & 1) * 32;
  int r = lane & 15, g = lane >> 4;

  const unsigned short* Ab = A + (long)b * sA;
  const unsigned short* Bb = Bt + (long)b * sB;

  int srow = t >> 2;            // 0..63
  int scol = (t & 3) * 8;

  f32x4 acc[4][2];
#pragma unroll
  for (int i = 0; i < 4; i++)
#pragma unroll
    for (int j = 0; j < 2; j++) acc[i][j] = (f32x4){0.f, 0.f, 0.f, 0.f};

  for (int k0 = 0; k0 < K; k0 += 64) {
    __syncthreads();
#pragma unroll
    for (int kh = 0; kh < 2; kh++) {
#pragma unroll
      for (int jj = 0; jj < 2; jj++) {
        __builtin_amdgcn_global_load_lds(
            GPTR(Ab + (long)(m0 + srow + jj * 64) * lda + k0 + kh * 32 + scol),
            LPTR(&As[kh * 4096 + jj * 2048 + t * 8]), 16, 0, 0);
      }
      __builtin_amdgcn_global_load_lds(
          GPTR(Bb + (long)(n0 + srow) * ldb + k0 + kh * 32 + scol),
          LPTR(&Bs[kh * 2048 + t * 8]), 16, 0, 0);
    }
    __syncthreads();
#pragma unroll
    for (int kh = 0; kh < 2; kh++) {
      bf16x8 af[4], bfr[2];
#pragma unroll
      for (int ti = 0; ti < 4; ti++)
        af[ti] = *(const bf16x8*)&As[kh * 4096 + (wm + ti * 16 + r) * 32 + g * 8];
#pragma unroll
      for (int tj = 0; tj < 2; tj++)
        bfr[tj] = *(const bf16x8*)&Bs[kh * 2048 + (wn + tj * 16 + r) * 32 + g * 8];
#pragma unroll
      for (int ti = 0; ti < 4; ti++)
#pragma unroll
        for (int tj = 0; tj < 2; tj++)
          acc[ti][tj] = __builtin_amdgcn_mfma_f32_16x16x32_bf16(af[ti], bfr[tj], acc[ti][tj], 0, 0, 0);
    }
  }

#pragma unroll
  for (int ti = 0; ti < 4; ti++) {
#pragma unroll
    for (int tj = 0; tj < 2; tj++) {
      int col = n0 + wn + tj * 16 + r;
      float bc = (BIAS_MODE == 1) ? bias[col] : 0.0f;
#pragma unroll
      for (int rr = 0; rr < 4; rr++) {
        int row = m0 + wm + ti * 16 + g * 4 + rr;
        float val = acc[ti][tj][rr] + bc;
        if (BIAS_MODE == 2) val += bias[row];
        long oidx = (long)b * sO + (long)row * ldo + col;
        if (F32OUT)
          ((float*)Out)[oidx] = val;
        else
          ((unsigned short*)Out)[oidx] = f2bf(val);
      }
    }
  }
}

// Fused scores + softmax + PV. Block = 32 Q-rows of one batch, 512 threads.
// Phase 1: S = Q K^T with K slab staged in LDS (8 waves = 2 rg x 4 ch).
// Phase 2: softmax in registers; P (bf16) written to LDS (row stride 1032).
// Phase 3: O = P V via MFMA, A-frags from LDS, B-frags direct from global Vt
//          (no barriers in the m-loop); store O as QKVt[c][n].
#define PS_LD 1032
__global__ __launch_bounds__(512, 4) void attn_fused(
    const unsigned short* __restrict__ Q,    // [B][1024][256] bf16
    const unsigned short* __restrict__ Km,   // [B][1024][256] bf16
    const unsigned short* __restrict__ Vt,   // [B][256][1024] bf16
    unsigned short* __restrict__ QKVt) {     // [B][256][1024] bf16
  __shared__ unsigned short ShBuf[32 * PS_LD];  // 66 KB; Ks uses first 64 KB
  __shared__ float red[4][2][16];
  int b = blockIdx.y;
  int n0 = blockIdx.x * 32;
  int t = threadIdx.x;
  int w = t >> 6, lane = t & 63;
  int rg = w >> 2, ch = w & 3;
  int r = lane & 15, g = lane >> 4;

  // Preload this wave's Q strip (16 rows x 256 k) as 8 A-fragments.
  const unsigned short* qbase = Q + ((long)b * NN + n0 + rg * 16 + r) * CC + g * 8;
  bf16x8 qf[8];
#pragma unroll
  for (int kk = 0; kk < 8; kk++) qf[kk] = *(const bf16x8*)(qbase + kk * 32);

  const unsigned short* kbase = Km + (long)b * NN * CC;
  int strow = t >> 2;           // 0..127
  int stcol = (t & 3) * 8;

  f32x4 acc[16];
#pragma unroll
  for (int tt = 0; tt < 16; tt++) acc[tt] = (f32x4){0.f, 0.f, 0.f, 0.f};

  for (int kk = 0; kk < 8; kk++) {
    __syncthreads();
#pragma unroll
    for (int jj = 0; jj < 8; jj++) {
      __builtin_amdgcn_global_load_lds(
          GPTR(kbase + (long)(strow + jj * 128) * CC + kk * 32 + stcol),
          LPTR(&ShBuf[(strow + jj * 128) * 32 + stcol]), 16, 0, 0);
    }
    __syncthreads();
#pragma unroll
    for (int tt = 0; tt < 16; tt++) {
      bf16x8 bv = *(const bf16x8*)&ShBuf[(ch * 256 + tt * 16 + r) * 32 + g * 8];
      acc[tt] = __builtin_amdgcn_mfma_f32_16x16x32_bf16(qf[kk], bv, acc[tt], 0, 0, 0);
    }
  }

  // ---- softmax (reduce within wave, then across the 4 ch waves) ----
  float mrow[4];
#pragma unroll
  for (int rr = 0; rr < 4; rr++) {
    float m = acc[0][rr];
#pragma unroll
    for (int tt = 1; tt < 16; tt++) m = fmaxf(m, acc[tt][rr]);
#pragma unroll
    for (int d = 1; d < 16; d <<= 1) m = fmaxf(m, __shfl_xor(m, d, 64));
    mrow[rr] = m;
  }
  if (r == 0) {
#pragma unroll
    for (int rr = 0; rr < 4; rr++) red[ch][rg][g * 4 + rr] = mrow[rr];
  }
  __syncthreads();
#pragma unroll
  for (int rr = 0; rr < 4; rr++) {
    float m = red[0][rg][g * 4 + rr];
#pragma unroll
    for (int c2 = 1; c2 < 4; c2++) m = fmaxf(m, red[c2][rg][g * 4 + rr]);
    mrow[rr] = m;
  }
  __syncthreads();  // WAR before sum overwrites red
  float ssum[4];
#pragma unroll
  for (int rr = 0; rr < 4; rr++) {
    float s = 0.f;
#pragma unroll
    for (int tt = 0; tt < 16; tt++) {
      float e = exp2f((acc[tt][rr] - mrow[rr]) * 1.44269504088896f);
      acc[tt][rr] = e;
      s += e;
    }
#pragma unroll
    for (int d = 1; d < 16; d <<= 1) s += __shfl_xor(s, d, 64);
    ssum[rr] = s;
  }
  if (r == 0) {
#pragma unroll
    for (int rr = 0; rr < 4; rr++) red[ch][rg][g * 4 + rr] = ssum[rr];
  }
  __syncthreads();
  // ---- phase 2: normalized P (bf16) into LDS, row-major stride PS_LD ----
#pragma unroll
  for (int rr = 0; rr < 4; rr++) {
    float s = red[0][rg][g * 4 + rr] + red[1][rg][g * 4 + rr] +
              red[2][rg][g * 4 + rr] + red[3][rg][g * 4 + rr];
    float inv = 1.0f / s;
    int prow = rg * 16 + g * 4 + rr;
#pragma unroll
    for (int tt = 0; tt < 16; tt++) {
      ShBuf[prow * PS_LD + ch * 256 + tt * 16 + r] = f2bf(acc[tt][rr] * inv);
    }
  }
  __syncthreads();

  // ---- phase 3: O = P V.  Wave w owns O cols [w*32, w*32+32), rows 0..32.
  const unsigned short* vbase = Vt + (long)b * NN * CC;  // [c][m]
  int cw = w * 32;
  f32x4 o[2][2];
#pragma unroll
  for (int i = 0; i < 2; i++)
#pragma unroll
    for (int j = 0; j < 2; j++) o[i][j] = (f32x4){0.f, 0.f, 0.f, 0.f};

  for (int m0 = 0; m0 < NN; m0 += 32) {
    bf16x8 ar[2], br[2];
#pragma unroll
    for (int bt = 0; bt < 2; bt++)
      br[bt] = *(const bf16x8*)(vbase + (long)(cw + bt * 16 + r) * NN + m0 + g * 8);
#pragma unroll
    for (int rt = 0; rt < 2; rt++)
      ar[rt] = *(const bf16x8*)&ShBuf[(rt * 16 + r) * PS_LD + m0 + g * 8];
#pragma unroll
    for (int rt = 0; rt < 2; rt++)
#pragma unroll
      for (int bt = 0; bt < 2; bt++)
        o[rt][bt] = __builtin_amdgcn_mfma_f32_16x16x32_bf16(ar[rt], br[bt], o[rt][bt], 0, 0, 0);
  }

  unsigned short* obase = QKVt + (long)b * NN * CC;  // [c][n]
#pragma unroll
  for (int rt = 0; rt < 2; rt++) {
#pragma unroll
    for (int bt = 0; bt < 2; bt++) {
      int c = cw + bt * 16 + r;
#pragma unroll
      for (int rr = 0; rr < 4; rr++) {
        int n = n0 + rt * 16 + g * 4 + rr;
        obase[(long)c * NN + n] = f2bf(o[rt][bt][rr]);
      }
    }
  }
}

extern "C" void kernel_launch(void* const* d_in, const int* in_sizes, int n_in,
                              void* d_out, int out_size, void* d_ws, size_t ws_size,
                              hipStream_t stream) {
  const float* x  = (const float*)d_in[0];
  const float* Wq = (const float*)d_in[1];
  const float* bq = (const float*)d_in[2];
  const float* Wk = (const float*)d_in[3];
  const float* bk = (const float*)d_in[4];
  const float* Wv = (const float*)d_in[5];
  const float* bv = (const float*)d_in[6];
  const float* Wp = (const float*)d_in[7];
  float* out = (float*)d_out;

  const long BNC = (long)BB * NN * CC;  // 4,194,304

  char* p = (char*)d_ws;
  unsigned short* xb   = (unsigned short*)p; p += BNC * 2;
  unsigned short* wqb  = (unsigned short*)p; p += CC * CC * 2;
  unsigned short* wkb  = (unsigned short*)p; p += CC * CC * 2;
  unsigned short* wvb  = (unsigned short*)p; p += CC * CC * 2;
  unsigned short* Amat = (unsigned short*)p; p += (long)NN * NN * 2;
  unsigned short* Qb   = (unsigned short*)p; p += BNC * 2;
  unsigned short* Kb   = (unsigned short*)p; p += BNC * 2;
  unsigned short* Vtb  = (unsigned short*)p; p += BNC * 2;   // [b][c][n]
  unsigned short* QKVt = (unsigned short*)p; p += BNC * 2;   // [b][c][n]

  // Stage 0: casts + Wp transpose
  cast_kernel<<<(int)((BNC + 255) / 256), 256, 0, stream>>>(x, xb, (int)BNC);
  cast_kernel<<<(CC * CC + 255) / 256, 256, 0, stream>>>(Wq, wqb, CC * CC);
  cast_kernel<<<(CC * CC + 255) / 256, 256, 0, stream>>>(Wk, wkb, CC * CC);
  cast_kernel<<<(CC * CC + 255) / 256, 256, 0, stream>>>(Wv, wvb, CC * CC);
  wp_transpose<<<dim3(NN / 32, 32), 256, 0, stream>>>(Wp, Amat);

  // Q = x @ Wq^T + bq : M=1024, N=256, K=256 -> [b][n][c]
  gemm_tile<1, 0><<<dim3(8, 4, BB), 256, 0, stream>>>(
      xb, CC, (long)NN * CC, wqb, CC, 0L, bq, Qb, CC, (long)NN * CC, CC);
  // K = x @ Wk^T + bk
  gemm_tile<1, 0><<<dim3(8, 4, BB), 256, 0, stream>>>(
      xb, CC, (long)NN * CC, wkb, CC, 0L, bk, Kb, CC, (long)NN * CC, CC);
  // Vt[c][n] = Wv[c].x[n] + bv[c] : M=256, N=1024, row bias
  gemm_tile<2, 0><<<dim3(2, 16, BB), 256, 0, stream>>>(
      wvb, CC, 0L, xb, CC, (long)NN * CC, bv, Vtb, NN, (long)NN * CC, CC);

  // Fused softmax(QK^T)·V -> QKVt[c][n]
  attn_fused<<<dim3(NN / 32, BB), 512, 0, stream>>>(Qb, Kb, Vtb, QKVt);

  // Z[hw][c] = sum_n Amat[hw][n] * QKVt[c][n] : M=1024, N=256, K=1024, f32 out
  gemm_tile<0, 1><<<dim3(8, 4, BB), 256, 0, stream>>>(
      Amat, NN, 0L, QKVt, NN, (long)NN * CC, nullptr,
      out, CC, (long)NN * CC, NN);
}

// Round 6
// 181.042 us; speedup vs baseline: 2.7191x; 1.0312x over previous
//
#include <hip/hip_runtime.h>
#include <hip/hip_bf16.h>

#define BB 16
#define NN 1024
#define CC 256

typedef __attribute__((ext_vector_type(8))) short bf16x8;
typedef __attribute__((ext_vector_type(4))) float f32x4;

#define GPTR(p) ((const __attribute__((address_space(1))) void*)(p))
#define LPTR(p) ((__attribute__((address_space(3))) void*)(p))

__device__ __forceinline__ unsigned short f2bf(float f) {
  union { float f; unsigned u; } v; v.f = f;
  unsigned r = v.u + 0x7FFFu + ((v.u >> 16) & 1u);
  return (unsigned short)(r >> 16);
}

// One kernel: cast x -> xb, Wq|Wk|Wv -> wqkvb (768x256 bf16), bq|bk|bv -> bqkv (f32).
__global__ void cast_all(const float* __restrict__ x,
                         const float* __restrict__ Wq, const float* __restrict__ Wk,
                         const float* __restrict__ Wv,
                         const float* __restrict__ bq, const float* __restrict__ bk,
                         const float* __restrict__ bv,
                         unsigned short* __restrict__ xb,
                         unsigned short* __restrict__ wqkvb,
                         float* __restrict__ bqkv) {
  const int NX = BB * NN * CC;        // 4,194,304
  const int NW = CC * CC;             // 65,536
  int i = blockIdx.x * blockDim.x + threadIdx.x;
  if (i < NX) { xb[i] = f2bf(x[i]); return; }
  int j = i - NX;
  if (j < 3 * NW) {
    const float* w = (j < NW) ? Wq : (j < 2 * NW ? Wk : Wv);
    wqkvb[j] = f2bf(w[j % NW]);
    return;
  }
  int jj = j - 3 * NW;
  if (jj < 3 * CC) {
    const float* bb = (jj < CC) ? bq : (jj < 2 * CC ? bk : bv);
    bqkv[jj] = bb[jj % CC];
  }
}

// Amat[(h*32+w)][n] = Wp[h][n][w]   (Wp: (32, 1024, 32) f32)
__global__ __launch_bounds__(256) void wp_transpose(const float* __restrict__ Wp,
                                                    unsigned short* __restrict__ Amat) {
  __shared__ float tile[32][33];
  int h = blockIdx.y;
  int n0 = blockIdx.x * 32;
#pragma unroll
  for (int j = 0; j < 4; j++) {
    int idx = threadIdx.x + j * 256;
    int a = idx >> 5, wc = idx & 31;
    tile[a][wc] = Wp[(size_t)h * (NN * 32) + (size_t)(n0 + a) * 32 + wc];
  }
  __syncthreads();
#pragma unroll
  for (int j = 0; j < 4; j++) {
    int idx = threadIdx.x + j * 256;
    int wc = idx >> 5, a = idx & 31;
    Amat[(size_t)(h * 32 + wc) * NN + n0 + a] = f2bf(tile[a][wc]);
  }
}

// Tiled GEMM: C[m][n] = sum_k A[m][k] * Bt[n][k] (+bias[col]). BM=128 BN=64 BK=64.
template <int BIAS_MODE, int F32OUT>
__global__ __launch_bounds__(256) void gemm_tile(
    const unsigned short* __restrict__ A, int lda, long sA,
    const unsigned short* __restrict__ Bt, int ldb, long sB,
    const float* __restrict__ bias,
    void* __restrict__ Out, int ldo, long sO, int K) {
  __shared__ unsigned short As[2 * 128 * 32];
  __shared__ unsigned short Bs[2 * 64 * 32];
  int b = blockIdx.z;
  int m0 = blockIdx.x * 128;
  int n0 = blockIdx.y * 64;
  int t = threadIdx.x;
  int w = t >> 6, lane = t & 63;
  int wm = (w >> 1) * 64, wn = (w & 1) * 32;
  int r = lane & 15, g = lane >> 4;

  const unsigned short* Ab = A + (long)b * sA;
  const unsigned short* Bb = Bt + (long)b * sB;

  int srow = t >> 2;
  int scol = (t & 3) * 8;

  f32x4 acc[4][2];
#pragma unroll
  for (int i = 0; i < 4; i++)
#pragma unroll
    for (int j = 0; j < 2; j++) acc[i][j] = (f32x4){0.f, 0.f, 0.f, 0.f};

  for (int k0 = 0; k0 < K; k0 += 64) {
    __syncthreads();
#pragma unroll
    for (int kh = 0; kh < 2; kh++) {
#pragma unroll
      for (int jj = 0; jj < 2; jj++) {
        __builtin_amdgcn_global_load_lds(
            GPTR(Ab + (long)(m0 + srow + jj * 64) * lda + k0 + kh * 32 + scol),
            LPTR(&As[kh * 4096 + jj * 2048 + t * 8]), 16, 0, 0);
      }
      __builtin_amdgcn_global_load_lds(
          GPTR(Bb + (long)(n0 + srow) * ldb + k0 + kh * 32 + scol),
          LPTR(&Bs[kh * 2048 + t * 8]), 16, 0, 0);
    }
    __syncthreads();
#pragma unroll
    for (int kh = 0; kh < 2; kh++) {
      bf16x8 af[4], bfr[2];
#pragma unroll
      for (int ti = 0; ti < 4; ti++)
        af[ti] = *(const bf16x8*)&As[kh * 4096 + (wm + ti * 16 + r) * 32 + g * 8];
#pragma unroll
      for (int tj = 0; tj < 2; tj++)
        bfr[tj] = *(const bf16x8*)&Bs[kh * 2048 + (wn + tj * 16 + r) * 32 + g * 8];
#pragma unroll
      for (int ti = 0; ti < 4; ti++)
#pragma unroll
        for (int tj = 0; tj < 2; tj++)
          acc[ti][tj] = __builtin_amdgcn_mfma_f32_16x16x32_bf16(af[ti], bfr[tj], acc[ti][tj], 0, 0, 0);
    }
  }

#pragma unroll
  for (int ti = 0; ti < 4; ti++) {
#pragma unroll
    for (int tj = 0; tj < 2; tj++) {
      int col = n0 + wn + tj * 16 + r;
      float bc = (BIAS_MODE == 1) ? bias[col] : 0.0f;
#pragma unroll
      for (int rr = 0; rr < 4; rr++) {
        int row = m0 + wm + ti * 16 + g * 4 + rr;
        float val = acc[ti][tj][rr] + bc;
        long oidx = (long)b * sO + (long)row * ldo + col;
        if (F32OUT)
          ((float*)Out)[oidx] = val;
        else
          ((unsigned short*)Out)[oidx] = f2bf(val);
      }
    }
  }
}

// Fused QKV projection: A = xb [n][256] per batch, Bt = wqkvb [768][256].
// Epilogue routes col segment 0 -> Qb[n][c], 1 -> Kb[n][c], 2 -> Vtb[c][n].
__global__ __launch_bounds__(256) void gemm_qkv(
    const unsigned short* __restrict__ A,
    const unsigned short* __restrict__ Bt,
    const float* __restrict__ bias,
    unsigned short* __restrict__ Qb, unsigned short* __restrict__ Kb,
    unsigned short* __restrict__ Vtb) {
  __shared__ unsigned short As[2 * 128 * 32];
  __shared__ unsigned short Bs[2 * 64 * 32];
  int b = blockIdx.z;
  int m0 = blockIdx.x * 128;
  int n0 = blockIdx.y * 64;
  int t = threadIdx.x;
  int w = t >> 6, lane = t & 63;
  int wm = (w >> 1) * 64, wn = (w & 1) * 32;
  int r = lane & 15, g = lane >> 4;

  const unsigned short* Ab = A + (long)b * NN * CC;
  int srow = t >> 2;
  int scol = (t & 3) * 8;

  f32x4 acc[4][2];
#pragma unroll
  for (int i = 0; i < 4; i++)
#pragma unroll
    for (int j = 0; j < 2; j++) acc[i][j] = (f32x4){0.f, 0.f, 0.f, 0.f};

  for (int k0 = 0; k0 < CC; k0 += 64) {
    __syncthreads();
#pragma unroll
    for (int kh = 0; kh < 2; kh++) {
#pragma unroll
      for (int jj = 0; jj < 2; jj++) {
        __builtin_amdgcn_global_load_lds(
            GPTR(Ab + (long)(m0 + srow + jj * 64) * CC + k0 + kh * 32 + scol),
            LPTR(&As[kh * 4096 + jj * 2048 + t * 8]), 16, 0, 0);
      }
      __builtin_amdgcn_global_load_lds(
          GPTR(Bt + (long)(n0 + srow) * CC + k0 + kh * 32 + scol),
          LPTR(&Bs[kh * 2048 + t * 8]), 16, 0, 0);
    }
    __syncthreads();
#pragma unroll
    for (int kh = 0; kh < 2; kh++) {
      bf16x8 af[4], bfr[2];
#pragma unroll
      for (int ti = 0; ti < 4; ti++)
        af[ti] = *(const bf16x8*)&As[kh * 4096 + (wm + ti * 16 + r) * 32 + g * 8];
#pragma unroll
      for (int tj = 0; tj < 2; tj++)
        bfr[tj] = *(const bf16x8*)&Bs[kh * 2048 + (wn + tj * 16 + r) * 32 + g * 8];
#pragma unroll
      for (int ti = 0; ti < 4; ti++)
#pragma unroll
        for (int tj = 0; tj < 2; tj++)
          acc[ti][tj] = __builtin_amdgcn_mfma_f32_16x16x32_bf16(af[ti], bfr[tj], acc[ti][tj], 0, 0, 0);
    }
  }

  int seg = n0 >> 8;  // block's 64-col span sits inside one 256-col segment
  unsigned short* QK = (seg == 0) ? Qb : Kb;
#pragma unroll
  for (int ti = 0; ti < 4; ti++) {
#pragma unroll
    for (int tj = 0; tj < 2; tj++) {
      int col = n0 + wn + tj * 16 + r;
      int c = col & 255;
      float bc = bias[col];
#pragma unroll
      for (int rr = 0; rr < 4; rr++) {
        int row = m0 + wm + ti * 16 + g * 4 + rr;
        float val = acc[ti][tj][rr] + bc;
        if (seg < 2)
          QK[(long)b * NN * CC + (long)row * CC + c] = f2bf(val);
        else
          Vtb[(long)b * NN * CC + (long)c * NN + row] = f2bf(val);
      }
    }
  }
}

// Fused scores + softmax + PV. Block = 32 Q-rows of one batch, 512 threads.
// Phase 1: S = Q K^T, K slab [1024][32] in LDS (conflict-free stride 64 B).
// Phase 2: P (bf16) into LDS at row stride 1024 with 16B-chunk XOR swizzle
//          (chunk' = chunk ^ (row&7)) -> conflict-free phase-3 reads.
// Phase 3: O = P V, A-frags from LDS, B-frags direct from global Vt.
__global__ __launch_bounds__(512, 4) void attn_fused(
    const unsigned short* __restrict__ Q,    // [B][1024][256] bf16
    const unsigned short* __restrict__ Km,   // [B][1024][256] bf16
    const unsigned short* __restrict__ Vt,   // [B][256][1024] bf16
    unsigned short* __restrict__ QKVt) {     // [B][256][1024] bf16
  __shared__ unsigned short ShBuf[32 * 1024];  // 64 KB (Ks phase 1 / P phase 2-3)
  __shared__ float red[4][2][16];
  int b = blockIdx.y;
  int n0 = blockIdx.x * 32;
  int t = threadIdx.x;
  int w = t >> 6, lane = t & 63;
  int rg = w >> 2, ch = w & 3;
  int r = lane & 15, g = lane >> 4;

  const unsigned short* qbase = Q + ((long)b * NN + n0 + rg * 16 + r) * CC + g * 8;
  bf16x8 qf[8];
#pragma unroll
  for (int kk = 0; kk < 8; kk++) qf[kk] = *(const bf16x8*)(qbase + kk * 32);

  const unsigned short* kbase = Km + (long)b * NN * CC;
  int strow = t >> 2;           // 0..127
  int stcol = (t & 3) * 8;

  f32x4 acc[16];
#pragma unroll
  for (int tt = 0; tt < 16; tt++) acc[tt] = (f32x4){0.f, 0.f, 0.f, 0.f};

  for (int kk = 0; kk < 8; kk++) {
    __syncthreads();
#pragma unroll
    for (int jj = 0; jj < 8; jj++) {
      __builtin_amdgcn_global_load_lds(
          GPTR(kbase + (long)(strow + jj * 128) * CC + kk * 32 + stcol),
          LPTR(&ShBuf[(strow + jj * 128) * 32 + stcol]), 16, 0, 0);
    }
    __syncthreads();
#pragma unroll
    for (int tt = 0; tt < 16; tt++) {
      bf16x8 bv = *(const bf16x8*)&ShBuf[(ch * 256 + tt * 16 + r) * 32 + g * 8];
      acc[tt] = __builtin_amdgcn_mfma_f32_16x16x32_bf16(qf[kk], bv, acc[tt], 0, 0, 0);
    }
  }

  // ---- softmax ----
  float mrow[4];
#pragma unroll
  for (int rr = 0; rr < 4; rr++) {
    float m = acc[0][rr];
#pragma unroll
    for (int tt = 1; tt < 16; tt++) m = fmaxf(m, acc[tt][rr]);
#pragma unroll
    for (int d = 1; d < 16; d <<= 1) m = fmaxf(m, __shfl_xor(m, d, 64));
    mrow[rr] = m;
  }
  if (r == 0) {
#pragma unroll
    for (int rr = 0; rr < 4; rr++) red[ch][rg][g * 4 + rr] = mrow[rr];
  }
  __syncthreads();
#pragma unroll
  for (int rr = 0; rr < 4; rr++) {
    float m = red[0][rg][g * 4 + rr];
#pragma unroll
    for (int c2 = 1; c2 < 4; c2++) m = fmaxf(m, red[c2][rg][g * 4 + rr]);
    mrow[rr] = m;
  }
  __syncthreads();  // WAR before sum overwrites red
  float ssum[4];
#pragma unroll
  for (int rr = 0; rr < 4; rr++) {
    float s = 0.f;
#pragma unroll
    for (int tt = 0; tt < 16; tt++) {
      float e = exp2f((acc[tt][rr] - mrow[rr]) * 1.44269504088896f);
      acc[tt][rr] = e;
      s += e;
    }
#pragma unroll
    for (int d = 1; d < 16; d <<= 1) s += __shfl_xor(s, d, 64);
    ssum[rr] = s;
  }
  if (r == 0) {
#pragma unroll
    for (int rr = 0; rr < 4; rr++) red[ch][rg][g * 4 + rr] = ssum[rr];
  }
  __syncthreads();
  // ---- phase 2: P (bf16) into LDS, stride 1024, XOR-swizzled 16B chunks ----
#pragma unroll
  for (int rr = 0; rr < 4; rr++) {
    float s = red[0][rg][g * 4 + rr] + red[1][rg][g * 4 + rr] +
              red[2][rg][g * 4 + rr] + red[3][rg][g * 4 + rr];
    float inv = 1.0f / s;
    int prow = rg * 16 + g * 4 + rr;
    int sw = prow & 7;
#pragma unroll
    for (int tt = 0; tt < 16; tt++) {
      int col = ch * 256 + tt * 16 + r;
      int chunk = (col >> 3) ^ sw;
      ShBuf[prow * 1024 + chunk * 8 + (col & 7)] = f2bf(acc[tt][rr] * inv);
    }
  }
  __syncthreads();

  // ---- phase 3: O = P V.  Wave w owns O cols [w*32, w*32+32), rows n0..n0+32.
  const unsigned short* vbase = Vt + (long)b * NN * CC;  // [c][m]
  int cw = w * 32;
  f32x4 o[2][2];
#pragma unroll
  for (int i = 0; i < 2; i++)
#pragma unroll
    for (int j = 0; j < 2; j++) o[i][j] = (f32x4){0.f, 0.f, 0.f, 0.f};

#pragma unroll 4
  for (int m0 = 0; m0 < NN; m0 += 32) {
    bf16x8 ar[2], br[2];
#pragma unroll
    for (int bt = 0; bt < 2; bt++)
      br[bt] = *(const bf16x8*)(vbase + (long)(cw + bt * 16 + r) * NN + m0 + g * 8);
#pragma unroll
    for (int rt = 0; rt < 2; rt++) {
      int prow = rt * 16 + r;
      int chunk = ((m0 >> 3) + g) ^ (prow & 7);
      ar[rt] = *(const bf16x8*)&ShBuf[prow * 1024 + chunk * 8];
    }
#pragma unroll
    for (int rt = 0; rt < 2; rt++)
#pragma unroll
      for (int bt = 0; bt < 2; bt++)
        o[rt][bt] = __builtin_amdgcn_mfma_f32_16x16x32_bf16(ar[rt], br[bt], o[rt][bt], 0, 0, 0);
  }

  unsigned short* obase = QKVt + (long)b * NN * CC;  // [c][n]
#pragma unroll
  for (int rt = 0; rt < 2; rt++) {
#pragma unroll
    for (int bt = 0; bt < 2; bt++) {
      int c = cw + bt * 16 + r;
#pragma unroll
      for (int rr = 0; rr < 4; rr++) {
        int n = n0 + rt * 16 + g * 4 + rr;
        obase[(long)c * NN + n] = f2bf(o[rt][bt][rr]);
      }
    }
  }
}

extern "C" void kernel_launch(void* const* d_in, const int* in_sizes, int n_in,
                              void* d_out, int out_size, void* d_ws, size_t ws_size,
                              hipStream_t stream) {
  const float* x  = (const float*)d_in[0];
  const float* Wq = (const float*)d_in[1];
  const float* bq = (const float*)d_in[2];
  const float* Wk = (const float*)d_in[3];
  const float* bk = (const float*)d_in[4];
  const float* Wv = (const float*)d_in[5];
  const float* bv = (const float*)d_in[6];
  const float* Wp = (const float*)d_in[7];
  float* out = (float*)d_out;

  const long BNC = (long)BB * NN * CC;  // 4,194,304

  char* p = (char*)d_ws;
  unsigned short* xb    = (unsigned short*)p; p += BNC * 2;
  unsigned short* wqkvb = (unsigned short*)p; p += 3L * CC * CC * 2;
  float*          bqkv  = (float*)p;          p += 4096;
  unsigned short* Amat  = (unsigned short*)p; p += (long)NN * NN * 2;
  unsigned short* Qb    = (unsigned short*)p; p += BNC * 2;
  unsigned short* Kb    = (unsigned short*)p; p += BNC * 2;
  unsigned short* Vtb   = (unsigned short*)p; p += BNC * 2;   // [b][c][n]
  unsigned short* QKVt  = (unsigned short*)p; p += BNC * 2;   // [b][c][n]

  const long TOT = BNC + 3L * CC * CC + 3 * CC;
  cast_all<<<(int)((TOT + 255) / 256), 256, 0, stream>>>(
      x, Wq, Wk, Wv, bq, bk, bv, xb, wqkvb, bqkv);
  wp_transpose<<<dim3(NN / 32, 32), 256, 0, stream>>>(Wp, Amat);

  // Fused QKV projection: M=1024, N=768, K=256 per batch
  gemm_qkv<<<dim3(8, 12, BB), 256, 0, stream>>>(xb, wqkvb, bqkv, Qb, Kb, Vtb);

  // Fused softmax(QK^T)·V -> QKVt[c][n]
  attn_fused<<<dim3(NN / 32, BB), 512, 0, stream>>>(Qb, Kb, Vtb, QKVt);

  // Z[hw][c] = sum_n Amat[hw][n] * QKVt[c][n] : M=1024, N=256, K=1024, f32 out
  gemm_tile<0, 1><<<dim3(8, 4, BB), 256, 0, stream>>>(
      Amat, NN, 0L, QKVt, NN, (long)NN * CC, nullptr,
      out, CC, (long)NN * CC, NN);
}